// Round 1
// baseline (1997.793 us; speedup 1.0000x reference)
//
#include <hip/hip_runtime.h>
#include <hip/hip_bf16.h>

#define B 64
#define T 2048
#define EMB 512
#define DEC 1024
#define ADIM 128
#define NFILT 32
#define KSIZE 31
#define KHALF 15

#define TILE_T 128
#define ECH 32
#define NTILE (T / TILE_T)   // 16
#define AS_STRIDE 36         // 32 + 4 pad: keeps A-reads 16B aligned, conflicts <= 2-way

// ws layout (floats):
#define WS_S 0                       // [B][ADIM]          8192
#define WS_E 8192                    // [B][T]             131072
#define WS_PM (8192 + 131072)        // [B][NTILE]         1024
#define WS_PS (WS_PM + B * NTILE)    // [B][NTILE]         1024
#define WS_PC (WS_PS + B * NTILE)    // [B][NTILE][EMB]    524288
// total = 665600 floats = 2.6 MB

// ---------------------------------------------------------------------------
// Kernel 1: S[b,a] = (query @ Wq)[b,a] + bq[a] + bm[a] + bl[a] + sum_f conv_b[f]*Wl[f,a]
// ---------------------------------------------------------------------------
__global__ __launch_bounds__(256) void k_qproj(
    const float* __restrict__ query, const float* __restrict__ Wq,
    const float* __restrict__ bq, const float* __restrict__ bm,
    const float* __restrict__ conv_b, const float* __restrict__ Wl,
    const float* __restrict__ bl, float* __restrict__ wsS)
{
  int b = blockIdx.x;
  int tid = threadIdx.x;
  int a = tid & 127;
  int h = tid >> 7;
  const float* q = query + (size_t)b * DEC;
  int e0 = h * (DEC / 2);
  float sum = 0.f;
  #pragma unroll 8
  for (int e = 0; e < DEC / 2; ++e) {
    sum = fmaf(q[e0 + e], Wq[(size_t)(e0 + e) * ADIM + a], sum);
  }
  __shared__ float red[256];
  red[tid] = sum;
  __syncthreads();
  if (h == 0) {
    float s = red[tid] + red[tid + 128];
    float cb = 0.f;
    #pragma unroll
    for (int f = 0; f < NFILT; ++f) cb = fmaf(conv_b[f], Wl[f * ADIM + a], cb);
    wsS[b * ADIM + a] = s + bq[a] + bm[a] + bl[a] + cb;
  }
}

// ---------------------------------------------------------------------------
// GEMM inner loop: acc[8][8] += As-rows (t = tx + 16*i) x Bs[e][a0..a0+7]
// ---------------------------------------------------------------------------
template <int KCNT>
__device__ inline void gemm_chunk(const float* __restrict__ As,
                                  const float* __restrict__ Bs,
                                  int tx, int a0, float acc[8][8])
{
  #pragma unroll
  for (int eg = 0; eg < KCNT; eg += 4) {
    float4 aa[8];
    #pragma unroll
    for (int i = 0; i < 8; ++i)
      aa[i] = *reinterpret_cast<const float4*>(&As[(tx + 16 * i) * AS_STRIDE + eg]);
    #pragma unroll
    for (int e = 0; e < 4; ++e) {
      float4 b0 = *reinterpret_cast<const float4*>(&Bs[(eg + e) * ADIM + a0]);
      float4 b1 = *reinterpret_cast<const float4*>(&Bs[(eg + e) * ADIM + a0 + 4]);
      #pragma unroll
      for (int i = 0; i < 8; ++i) {
        float av = (e == 0) ? aa[i].x : (e == 1) ? aa[i].y : (e == 2) ? aa[i].z : aa[i].w;
        acc[i][0] = fmaf(av, b0.x, acc[i][0]);
        acc[i][1] = fmaf(av, b0.y, acc[i][1]);
        acc[i][2] = fmaf(av, b0.z, acc[i][2]);
        acc[i][3] = fmaf(av, b0.w, acc[i][3]);
        acc[i][4] = fmaf(av, b1.x, acc[i][4]);
        acc[i][5] = fmaf(av, b1.y, acc[i][5]);
        acc[i][6] = fmaf(av, b1.z, acc[i][6]);
        acc[i][7] = fmaf(av, b1.w, acc[i][7]);
      }
    }
  }
}

// ---------------------------------------------------------------------------
// Kernel 2: per (b, 128-row tile): energies + online-softmax partials + context partial
// ---------------------------------------------------------------------------
__global__ __launch_bounds__(256, 3) void k_energy(
    const float* __restrict__ memory, const float* __restrict__ awc,
    const float* __restrict__ mask, const float* __restrict__ Wm,
    const float* __restrict__ convk, const float* __restrict__ Wl,
    const float* __restrict__ V, const float* __restrict__ bV,
    const float* __restrict__ wsS, float* __restrict__ energies,
    float* __restrict__ pm, float* __restrict__ psum, float* __restrict__ pc)
{
  // LDS: As [128][36] | Bs [32][128] | scr(max(992+158, 256)) | r2[8]
  __shared__ __align__(16) float smem[4608 + 4096 + 1150 + 8];
  float* As  = smem;
  float* Bs  = smem + 4608;
  float* scr = smem + 8704;
  float* r2  = smem + 9854;

  int tid = threadIdx.x;
  int tile = blockIdx.x;
  int b = blockIdx.y;
  int t0 = tile * TILE_T;
  int tx = tid >> 4;        // 0..15 -> rows t = tx + 16*i
  int ty = tid & 15;        // a cols ty*8 .. ty*8+7
  int a0 = ty * 8;

  float* ckS  = scr;        // [31][32] = 992 (loc phase only)
  float* awcS = scr + 992;  // [158]          (loc phase only)

  for (int i = tid; i < KSIZE * NFILT; i += 256) ckS[i] = convk[i];
  for (int i = tid; i < TILE_T + KSIZE - 1; i += 256) {
    int tg = t0 + i - KHALF;
    awcS[i] = (tg >= 0 && tg < T) ? awc[(size_t)b * T + tg] : 0.f;
  }

  // init acc with t-independent sum S[b,a]
  float acc[8][8];
  {
    const float* Sb = wsS + b * ADIM + a0;
    float sv[8];
    #pragma unroll
    for (int j = 0; j < 8; ++j) sv[j] = Sb[j];
    #pragma unroll
    for (int i = 0; i < 8; ++i)
      #pragma unroll
      for (int j = 0; j < 8; ++j) acc[i][j] = sv[j];
  }

  const int tl = tid >> 1;        // staging row 0..127
  const int el = (tid & 1) * 16;  // staging e base

  // main GEMM over EMB in chunks of 32
  for (int ec = 0; ec < EMB / ECH; ++ec) {
    __syncthreads();
    const float* gsrc = memory + ((size_t)b * T + t0 + tl) * EMB + ec * ECH + el;
    #pragma unroll
    for (int k = 0; k < 4; ++k)
      *reinterpret_cast<float4*>(&As[tl * AS_STRIDE + el + k * 4]) =
          *reinterpret_cast<const float4*>(gsrc + k * 4);
    const float* wsrc = Wm + (size_t)ec * ECH * ADIM;
    #pragma unroll
    for (int i = 0; i < 4; ++i)
      *reinterpret_cast<float4*>(&Bs[tid * 4 + i * 1024]) =
          *reinterpret_cast<const float4*>(wsrc + tid * 4 + i * 1024);
    __syncthreads();
    gemm_chunk<ECH>(As, Bs, tx, a0, acc);
  }

  // location phase: conv(awc) -> As[t][f], Wl -> Bs[f][a]; same inner loop, K=32
  __syncthreads();
  {
    int t = tid >> 1;
    int f0 = (tid & 1) * 16;
    float lf[16];
    #pragma unroll
    for (int j = 0; j < 16; ++j) lf[j] = 0.f;
    for (int k = 0; k < KSIZE; ++k) {
      float av = awcS[t + k];
      #pragma unroll
      for (int j = 0; j < 16; ++j) lf[j] = fmaf(av, ckS[k * NFILT + f0 + j], lf[j]);
    }
    #pragma unroll
    for (int j = 0; j < 16; j += 4)
      *reinterpret_cast<float4*>(&As[t * AS_STRIDE + f0 + j]) =
          make_float4(lf[j], lf[j + 1], lf[j + 2], lf[j + 3]);
    #pragma unroll
    for (int i = 0; i < 4; ++i)
      *reinterpret_cast<float4*>(&Bs[tid * 4 + i * 1024]) =
          *reinterpret_cast<const float4*>(Wl + tid * 4 + i * 1024);
  }
  __syncthreads();
  gemm_chunk<NFILT>(As, Bs, tx, a0, acc);

  // epilogue: energies
  float* eT = scr;        // [128] (scr reuse; conv data dead now)
  float* pT = scr + 128;  // [128]
  {
    float vv[8];
    #pragma unroll
    for (int j = 0; j < 8; ++j) vv[j] = V[a0 + j];
    float bVv = bV[0];
    #pragma unroll
    for (int i = 0; i < 8; ++i) {
      float s = 0.f;
      #pragma unroll
      for (int j = 0; j < 8; ++j) s = fmaf(tanhf(acc[i][j]), vv[j], s);
      #pragma unroll
      for (int m = 1; m < 16; m <<= 1) s += __shfl_xor(s, m, 64);
      if (ty == 0) {
        int t = tx + 16 * i;
        float E = s + bVv + mask[(size_t)b * T + t0 + t] * (-1e9f);
        eT[t] = E;
        energies[(size_t)b * T + t0 + t] = E;
      }
    }
  }
  __syncthreads();

  // tile softmax stats over 128 energies (2 waves), then context partial
  float E2 = -INFINITY;
  if (tid < 128) E2 = eT[tid];
  float mw = E2;
  #pragma unroll
  for (int d = 1; d < 64; d <<= 1) mw = fmaxf(mw, __shfl_xor(mw, d, 64));
  if (tid < 128 && (tid & 63) == 0) r2[tid >> 6] = mw;
  __syncthreads();
  float mblk = fmaxf(r2[0], r2[1]);
  float pv = 0.f;
  if (tid < 128) { pv = expf(E2 - mblk); pT[tid] = pv; }
  float sw = pv;
  #pragma unroll
  for (int d = 1; d < 64; d <<= 1) sw += __shfl_xor(sw, d, 64);
  if (tid < 128 && (tid & 63) == 0) r2[4 + (tid >> 6)] = sw;
  __syncthreads();
  if (tid == 0) {
    pm[b * NTILE + tile] = mblk;
    psum[b * NTILE + tile] = r2[4] + r2[5];
  }
  // context partial: c[e] = sum_t p_t * memory[b, t0+t, e]  (tile is L2-hot)
  {
    int e = tid * 2;
    float c0 = 0.f, c1 = 0.f;
    const float* mrow = memory + ((size_t)b * T + t0) * EMB + e;
    for (int t = 0; t < TILE_T; ++t) {
      float p = pT[t];
      float2 mv = *reinterpret_cast<const float2*>(mrow + (size_t)t * EMB);
      c0 = fmaf(p, mv.x, c0);
      c1 = fmaf(p, mv.y, c1);
    }
    float* dst = pc + ((size_t)b * NTILE + tile) * EMB + e;
    dst[0] = c0;
    dst[1] = c1;
  }
}

// ---------------------------------------------------------------------------
// Kernel 3: combine partials -> context, weights
// ---------------------------------------------------------------------------
__global__ __launch_bounds__(256) void k_final(
    const float* __restrict__ energies, const float* __restrict__ pm,
    const float* __restrict__ psum, const float* __restrict__ pc,
    float* __restrict__ out)
{
  int b = blockIdx.x;
  int tid = threadIdx.x;
  __shared__ float scale[NTILE];
  __shared__ float MS[2];
  if (tid < 64) {
    float m = (tid < NTILE) ? pm[b * NTILE + tid] : -INFINITY;
    float M = m;
    #pragma unroll
    for (int d = 1; d < 64; d <<= 1) M = fmaxf(M, __shfl_xor(M, d, 64));
    float sc = (tid < NTILE) ? psum[b * NTILE + tid] * expf(m - M) : 0.f;
    float S = sc;
    #pragma unroll
    for (int d = 1; d < 64; d <<= 1) S += __shfl_xor(S, d, 64);
    if (tid < NTILE) scale[tid] = expf(m - M);
    if (tid == 0) { MS[0] = M; MS[1] = S; }
  }
  __syncthreads();
  float M = MS[0];
  float Sinv = 1.f / MS[1];
  // context: e = tid*2, tid*2+1
  {
    int e = tid * 2;
    float c0 = 0.f, c1 = 0.f;
    const float* src = pc + (size_t)b * NTILE * EMB + e;
    #pragma unroll
    for (int p = 0; p < NTILE; ++p) {
      float s = scale[p];
      float2 v = *reinterpret_cast<const float2*>(src + p * EMB);
      c0 = fmaf(s, v.x, c0);
      c1 = fmaf(s, v.y, c1);
    }
    out[(size_t)b * EMB + e] = c0 * Sinv;
    out[(size_t)b * EMB + e + 1] = c1 * Sinv;
  }
  // weights: t = tid*8 .. +7
  {
    float* wout = out + B * EMB;
    const float* Eb = energies + (size_t)b * T;
    int t = tid * 8;
    float4 e0 = *reinterpret_cast<const float4*>(Eb + t);
    float4 e1 = *reinterpret_cast<const float4*>(Eb + t + 4);
    float4 w0 = make_float4(expf(e0.x - M) * Sinv, expf(e0.y - M) * Sinv,
                            expf(e0.z - M) * Sinv, expf(e0.w - M) * Sinv);
    float4 w1 = make_float4(expf(e1.x - M) * Sinv, expf(e1.y - M) * Sinv,
                            expf(e1.z - M) * Sinv, expf(e1.w - M) * Sinv);
    *reinterpret_cast<float4*>(wout + (size_t)b * T + t) = w0;
    *reinterpret_cast<float4*>(wout + (size_t)b * T + t + 4) = w1;
  }
}

// ---------------------------------------------------------------------------
extern "C" void kernel_launch(void* const* d_in, const int* in_sizes, int n_in,
                              void* d_out, int out_size, void* d_ws, size_t ws_size,
                              hipStream_t stream)
{
  const float* query  = (const float*)d_in[0];
  const float* memory = (const float*)d_in[1];
  const float* awc    = (const float*)d_in[2];
  const float* mask   = (const float*)d_in[3];
  const float* Wq     = (const float*)d_in[4];
  const float* bq     = (const float*)d_in[5];
  const float* Wm     = (const float*)d_in[6];
  const float* bm     = (const float*)d_in[7];
  const float* convk  = (const float*)d_in[8];
  const float* convb  = (const float*)d_in[9];
  const float* Wl     = (const float*)d_in[10];
  const float* bl     = (const float*)d_in[11];
  const float* V      = (const float*)d_in[12];
  const float* bV     = (const float*)d_in[13];
  float* out = (float*)d_out;
  float* ws  = (float*)d_ws;

  float* wsS      = ws + WS_S;
  float* energies = ws + WS_E;
  float* pm       = ws + WS_PM;
  float* psum     = ws + WS_PS;
  float* pc       = ws + WS_PC;

  k_qproj<<<B, 256, 0, stream>>>(query, Wq, bq, bm, convb, Wl, bl, wsS);
  dim3 g2(NTILE, B);
  k_energy<<<g2, 256, 0, stream>>>(memory, awc, mask, Wm, convk, Wl, V, bV,
                                   wsS, energies, pm, psum, pc);
  k_final<<<B, 256, 0, stream>>>(energies, pm, psum, pc, out);
}

// Round 2
// 1703.539 us; speedup vs baseline: 1.1727x; 1.1727x over previous
//
#include <hip/hip_runtime.h>
#include <hip/hip_bf16.h>

#define B 64
#define T 2048
#define EMB 512
#define DEC 1024
#define ADIM 128
#define NFILT 32
#define KSIZE 31
#define KHALF 15

#define TILE_T 128
#define ECH 32
#define NTILE (T / TILE_T)   // 16
#define AS_STRIDE 36         // 32 + 4 pad: keeps A-reads 16B aligned, conflicts <= 2-way

// ws layout (floats):
#define WS_S 0                       // [B][ADIM]          8192
#define WS_E 8192                    // [B][T]             131072
#define WS_PM (8192 + 131072)        // [B][NTILE]         1024
#define WS_PS (WS_PM + B * NTILE)    // [B][NTILE]         1024
#define WS_PC (WS_PS + B * NTILE)    // [B][NTILE][EMB]    524288
// total = 665600 floats = 2.6 MB

// ---------------------------------------------------------------------------
// Kernel 1: S[b,a] = (query @ Wq)[b,a] + bq[a] + bm[a] + bl[a] + sum_f conv_b[f]*Wl[f,a]
// ---------------------------------------------------------------------------
__global__ __launch_bounds__(256) void k_qproj(
    const float* __restrict__ query, const float* __restrict__ Wq,
    const float* __restrict__ bq, const float* __restrict__ bm,
    const float* __restrict__ conv_b, const float* __restrict__ Wl,
    const float* __restrict__ bl, float* __restrict__ wsS)
{
  int b = blockIdx.x;
  int tid = threadIdx.x;
  int a = tid & 127;
  int h = tid >> 7;
  const float* q = query + (size_t)b * DEC;
  int e0 = h * (DEC / 2);
  float sum = 0.f;
  #pragma unroll 8
  for (int e = 0; e < DEC / 2; ++e) {
    sum = fmaf(q[e0 + e], Wq[(size_t)(e0 + e) * ADIM + a], sum);
  }
  __shared__ float red[256];
  red[tid] = sum;
  __syncthreads();
  if (h == 0) {
    float s = red[tid] + red[tid + 128];
    float cb = 0.f;
    #pragma unroll
    for (int f = 0; f < NFILT; ++f) cb = fmaf(conv_b[f], Wl[f * ADIM + a], cb);
    wsS[b * ADIM + a] = s + bq[a] + bm[a] + bl[a] + cb;
  }
}

// ---------------------------------------------------------------------------
// GEMM inner loop: acc[8][8] += As-rows (t = tx + 16*i) x Bs[e][a0..a0+7]
// ---------------------------------------------------------------------------
template <int KCNT>
__device__ inline void gemm_chunk(const float* __restrict__ As,
                                  const float* __restrict__ Bs,
                                  int tx, int a0, float acc[8][8])
{
  #pragma unroll
  for (int eg = 0; eg < KCNT; eg += 4) {
    float4 aa[8];
    #pragma unroll
    for (int i = 0; i < 8; ++i)
      aa[i] = *reinterpret_cast<const float4*>(&As[(tx + 16 * i) * AS_STRIDE + eg]);
    #pragma unroll
    for (int e = 0; e < 4; ++e) {
      float4 b0 = *reinterpret_cast<const float4*>(&Bs[(eg + e) * ADIM + a0]);
      float4 b1 = *reinterpret_cast<const float4*>(&Bs[(eg + e) * ADIM + a0 + 4]);
      #pragma unroll
      for (int i = 0; i < 8; ++i) {
        float av = (e == 0) ? aa[i].x : (e == 1) ? aa[i].y : (e == 2) ? aa[i].z : aa[i].w;
        acc[i][0] = fmaf(av, b0.x, acc[i][0]);
        acc[i][1] = fmaf(av, b0.y, acc[i][1]);
        acc[i][2] = fmaf(av, b0.z, acc[i][2]);
        acc[i][3] = fmaf(av, b0.w, acc[i][3]);
        acc[i][4] = fmaf(av, b1.x, acc[i][4]);
        acc[i][5] = fmaf(av, b1.y, acc[i][5]);
        acc[i][6] = fmaf(av, b1.z, acc[i][6]);
        acc[i][7] = fmaf(av, b1.w, acc[i][7]);
      }
    }
  }
}

// ---------------------------------------------------------------------------
// Kernel 2: per (b, 128-row tile): energies + online-softmax partials + context partial
// __launch_bounds__(256, 2): cap 256 VGPR. (256,3) made the allocator clamp to
// 84 VGPR and spill acc[8][8] in the K-loop -> 733 MB scratch writes/dispatch.
// ---------------------------------------------------------------------------
__global__ __launch_bounds__(256, 2) void k_energy(
    const float* __restrict__ memory, const float* __restrict__ awc,
    const float* __restrict__ mask, const float* __restrict__ Wm,
    const float* __restrict__ convk, const float* __restrict__ Wl,
    const float* __restrict__ V, const float* __restrict__ bV,
    const float* __restrict__ wsS, float* __restrict__ energies,
    float* __restrict__ pm, float* __restrict__ psum, float* __restrict__ pc)
{
  // LDS: As [128][36] | Bs [32][128] | scr(max(992+158, 256)) | r2[8]
  __shared__ __align__(16) float smem[4608 + 4096 + 1150 + 8];
  float* As  = smem;
  float* Bs  = smem + 4608;
  float* scr = smem + 8704;
  float* r2  = smem + 9854;

  int tid = threadIdx.x;
  int tile = blockIdx.x;
  int b = blockIdx.y;
  int t0 = tile * TILE_T;
  int tx = tid >> 4;        // 0..15 -> rows t = tx + 16*i
  int ty = tid & 15;        // a cols ty*8 .. ty*8+7
  int a0 = ty * 8;

  float* ckS  = scr;        // [31][32] = 992 (loc phase only)
  float* awcS = scr + 992;  // [158]          (loc phase only)

  for (int i = tid; i < KSIZE * NFILT; i += 256) ckS[i] = convk[i];
  for (int i = tid; i < TILE_T + KSIZE - 1; i += 256) {
    int tg = t0 + i - KHALF;
    awcS[i] = (tg >= 0 && tg < T) ? awc[(size_t)b * T + tg] : 0.f;
  }

  // init acc with t-independent sum S[b,a]
  float acc[8][8];
  {
    const float* Sb = wsS + b * ADIM + a0;
    float sv[8];
    #pragma unroll
    for (int j = 0; j < 8; ++j) sv[j] = Sb[j];
    #pragma unroll
    for (int i = 0; i < 8; ++i)
      #pragma unroll
      for (int j = 0; j < 8; ++j) acc[i][j] = sv[j];
  }

  const int tl = tid >> 1;        // staging row 0..127
  const int el = (tid & 1) * 16;  // staging e base

  // main GEMM over EMB in chunks of 32, issue-early / write-late staging
  {
    float4 ra[4], rb[4];
    const float* gsrc0 = memory + ((size_t)b * T + t0 + tl) * EMB + el;
    #pragma unroll
    for (int k = 0; k < 4; ++k)
      ra[k] = *reinterpret_cast<const float4*>(gsrc0 + k * 4);
    #pragma unroll
    for (int i = 0; i < 4; ++i)
      rb[i] = *reinterpret_cast<const float4*>(Wm + tid * 4 + i * 1024);

    for (int ec = 0; ec < EMB / ECH; ++ec) {
      __syncthreads();   // previous compute done; As/Bs free
      #pragma unroll
      for (int k = 0; k < 4; ++k)
        *reinterpret_cast<float4*>(&As[tl * AS_STRIDE + el + k * 4]) = ra[k];
      #pragma unroll
      for (int i = 0; i < 4; ++i)
        *reinterpret_cast<float4*>(&Bs[tid * 4 + i * 1024]) = rb[i];
      __syncthreads();
      if (ec + 1 < EMB / ECH) {  // issue next chunk's loads before computing
        const float* gsrc = memory + ((size_t)b * T + t0 + tl) * EMB + (ec + 1) * ECH + el;
        #pragma unroll
        for (int k = 0; k < 4; ++k)
          ra[k] = *reinterpret_cast<const float4*>(gsrc + k * 4);
        const float* wsrc = Wm + (size_t)(ec + 1) * ECH * ADIM;
        #pragma unroll
        for (int i = 0; i < 4; ++i)
          rb[i] = *reinterpret_cast<const float4*>(wsrc + tid * 4 + i * 1024);
      }
      gemm_chunk<ECH>(As, Bs, tx, a0, acc);
    }
  }

  // location phase: conv(awc) -> As[t][f], Wl -> Bs[f][a]; same inner loop, K=32
  __syncthreads();
  {
    int t = tid >> 1;
    int f0 = (tid & 1) * 16;
    float lf[16];
    #pragma unroll
    for (int j = 0; j < 16; ++j) lf[j] = 0.f;
    for (int k = 0; k < KSIZE; ++k) {
      float av = awcS[t + k];
      #pragma unroll
      for (int j = 0; j < 16; ++j) lf[j] = fmaf(av, ckS[k * NFILT + f0 + j], lf[j]);
    }
    #pragma unroll
    for (int j = 0; j < 16; j += 4)
      *reinterpret_cast<float4*>(&As[t * AS_STRIDE + f0 + j]) =
          make_float4(lf[j], lf[j + 1], lf[j + 2], lf[j + 3]);
    #pragma unroll
    for (int i = 0; i < 4; ++i)
      *reinterpret_cast<float4*>(&Bs[tid * 4 + i * 1024]) =
          *reinterpret_cast<const float4*>(Wl + tid * 4 + i * 1024);
  }
  __syncthreads();
  gemm_chunk<NFILT>(As, Bs, tx, a0, acc);

  // epilogue: energies
  float* eT = scr;        // [128] (scr reuse; conv data dead now)
  float* pT = scr + 128;  // [128]
  {
    float vv[8];
    #pragma unroll
    for (int j = 0; j < 8; ++j) vv[j] = V[a0 + j];
    float bVv = bV[0];
    #pragma unroll
    for (int i = 0; i < 8; ++i) {
      float s = 0.f;
      #pragma unroll
      for (int j = 0; j < 8; ++j) s = fmaf(tanhf(acc[i][j]), vv[j], s);
      #pragma unroll
      for (int m = 1; m < 16; m <<= 1) s += __shfl_xor(s, m, 64);
      if (ty == 0) {
        int t = tx + 16 * i;
        float E = s + bVv + mask[(size_t)b * T + t0 + t] * (-1e9f);
        eT[t] = E;
        energies[(size_t)b * T + t0 + t] = E;
      }
    }
  }
  __syncthreads();

  // tile softmax stats over 128 energies (2 waves), then context partial
  float E2 = -INFINITY;
  if (tid < 128) E2 = eT[tid];
  float mw = E2;
  #pragma unroll
  for (int d = 1; d < 64; d <<= 1) mw = fmaxf(mw, __shfl_xor(mw, d, 64));
  if (tid < 128 && (tid & 63) == 0) r2[tid >> 6] = mw;
  __syncthreads();
  float mblk = fmaxf(r2[0], r2[1]);
  float pv = 0.f;
  if (tid < 128) { pv = expf(E2 - mblk); pT[tid] = pv; }
  float sw = pv;
  #pragma unroll
  for (int d = 1; d < 64; d <<= 1) sw += __shfl_xor(sw, d, 64);
  if (tid < 128 && (tid & 63) == 0) r2[4 + (tid >> 6)] = sw;
  __syncthreads();
  if (tid == 0) {
    pm[b * NTILE + tile] = mblk;
    psum[b * NTILE + tile] = r2[4] + r2[5];
  }
  // context partial: c[e] = sum_t p_t * memory[b, t0+t, e]  (tile is L2-hot)
  {
    int e = tid * 2;
    float c0 = 0.f, c1 = 0.f;
    const float* mrow = memory + ((size_t)b * T + t0) * EMB + e;
    #pragma unroll 4
    for (int t = 0; t < TILE_T; ++t) {
      float p = pT[t];
      float2 mv = *reinterpret_cast<const float2*>(mrow + (size_t)t * EMB);
      c0 = fmaf(p, mv.x, c0);
      c1 = fmaf(p, mv.y, c1);
    }
    float* dst = pc + ((size_t)b * NTILE + tile) * EMB + e;
    dst[0] = c0;
    dst[1] = c1;
  }
}

// ---------------------------------------------------------------------------
// Kernel 3: combine partials -> context, weights
// ---------------------------------------------------------------------------
__global__ __launch_bounds__(256) void k_final(
    const float* __restrict__ energies, const float* __restrict__ pm,
    const float* __restrict__ psum, const float* __restrict__ pc,
    float* __restrict__ out)
{
  int b = blockIdx.x;
  int tid = threadIdx.x;
  __shared__ float scale[NTILE];
  __shared__ float MS[2];
  if (tid < 64) {
    float m = (tid < NTILE) ? pm[b * NTILE + tid] : -INFINITY;
    float M = m;
    #pragma unroll
    for (int d = 1; d < 64; d <<= 1) M = fmaxf(M, __shfl_xor(M, d, 64));
    float sc = (tid < NTILE) ? psum[b * NTILE + tid] * expf(m - M) : 0.f;
    float S = sc;
    #pragma unroll
    for (int d = 1; d < 64; d <<= 1) S += __shfl_xor(S, d, 64);
    if (tid < NTILE) scale[tid] = expf(m - M);
    if (tid == 0) { MS[0] = M; MS[1] = S; }
  }
  __syncthreads();
  float M = MS[0];
  float Sinv = 1.f / MS[1];
  // context: e = tid*2, tid*2+1
  {
    int e = tid * 2;
    float c0 = 0.f, c1 = 0.f;
    const float* src = pc + (size_t)b * NTILE * EMB + e;
    #pragma unroll
    for (int p = 0; p < NTILE; ++p) {
      float s = scale[p];
      float2 v = *reinterpret_cast<const float2*>(src + p * EMB);
      c0 = fmaf(s, v.x, c0);
      c1 = fmaf(s, v.y, c1);
    }
    out[(size_t)b * EMB + e] = c0 * Sinv;
    out[(size_t)b * EMB + e + 1] = c1 * Sinv;
  }
  // weights: t = tid*8 .. +7
  {
    float* wout = out + B * EMB;
    const float* Eb = energies + (size_t)b * T;
    int t = tid * 8;
    float4 e0 = *reinterpret_cast<const float4*>(Eb + t);
    float4 e1 = *reinterpret_cast<const float4*>(Eb + t + 4);
    float4 w0 = make_float4(expf(e0.x - M) * Sinv, expf(e0.y - M) * Sinv,
                            expf(e0.z - M) * Sinv, expf(e0.w - M) * Sinv);
    float4 w1 = make_float4(expf(e1.x - M) * Sinv, expf(e1.y - M) * Sinv,
                            expf(e1.z - M) * Sinv, expf(e1.w - M) * Sinv);
    *reinterpret_cast<float4*>(wout + (size_t)b * T + t) = w0;
    *reinterpret_cast<float4*>(wout + (size_t)b * T + t + 4) = w1;
  }
}

// ---------------------------------------------------------------------------
extern "C" void kernel_launch(void* const* d_in, const int* in_sizes, int n_in,
                              void* d_out, int out_size, void* d_ws, size_t ws_size,
                              hipStream_t stream)
{
  const float* query  = (const float*)d_in[0];
  const float* memory = (const float*)d_in[1];
  const float* awc    = (const float*)d_in[2];
  const float* mask   = (const float*)d_in[3];
  const float* Wq     = (const float*)d_in[4];
  const float* bq     = (const float*)d_in[5];
  const float* Wm     = (const float*)d_in[6];
  const float* bm     = (const float*)d_in[7];
  const float* convk  = (const float*)d_in[8];
  const float* convb  = (const float*)d_in[9];
  const float* Wl     = (const float*)d_in[10];
  const float* bl     = (const float*)d_in[11];
  const float* V      = (const float*)d_in[12];
  const float* bV     = (const float*)d_in[13];
  float* out = (float*)d_out;
  float* ws  = (float*)d_ws;

  float* wsS      = ws + WS_S;
  float* energies = ws + WS_E;
  float* pm       = ws + WS_PM;
  float* psum     = ws + WS_PS;
  float* pc       = ws + WS_PC;

  k_qproj<<<B, 256, 0, stream>>>(query, Wq, bq, bm, convb, Wl, bl, wsS);
  dim3 g2(NTILE, B);
  k_energy<<<g2, 256, 0, stream>>>(memory, awc, mask, Wm, convk, Wl, V, bV,
                                   wsS, energies, pm, psum, pc);
  k_final<<<B, 256, 0, stream>>>(energies, pm, psum, pc, out);
}

// Round 3
// 641.612 us; speedup vs baseline: 3.1137x; 2.6551x over previous
//
#include <hip/hip_runtime.h>
#include <hip/hip_bf16.h>

#define B 64
#define T 2048
#define EMB 512
#define DEC 1024
#define ADIM 128
#define NFILT 32
#define KSIZE 31
#define KHALF 15

#define TILE_T 128
#define NTILE (T / TILE_T)   // 16
#define APAD 40              // A-row stride in bf16 (80 B): 16B-aligned, 2-way-conflict banks

typedef __bf16 bf16x8 __attribute__((ext_vector_type(8)));
typedef float f32x4 __attribute__((ext_vector_type(4)));

// ws layout (float units):
#define WS_S 0                           // [B][ADIM]            8192
#define WS_E 8192                        // [B][T]               131072
#define WS_PM (8192 + 131072)            // [B][NTILE]           1024
#define WS_PS (WS_PM + B * NTILE)       // [B][NTILE]           1024
#define WS_PC (WS_PS + B * NTILE)       // [B][NTILE][EMB]      524288
#define WS_WMT_H (WS_PC + B * NTILE * EMB)   // bf16 [128][512]  32768 floats
#define WS_WMT_L (WS_WMT_H + ADIM * EMB / 2) // bf16 [128][512]  32768
#define WS_WLT_H (WS_WMT_L + ADIM * EMB / 2) // bf16 [128][32]   1024
#define WS_WLT_L (WS_WLT_H + ADIM * NFILT / 2) // bf16 [128][32] 1024
// total ~733k floats = 2.93 MB

__device__ inline void cvt8(const float4& u, const float4& v, bf16x8& h, bf16x8& l) {
  float xs[8] = {u.x, u.y, u.z, u.w, v.x, v.y, v.z, v.w};
  #pragma unroll
  for (int j = 0; j < 8; ++j) {
    __bf16 hh = (__bf16)xs[j];
    h[j] = hh;
    l[j] = (__bf16)(xs[j] - (float)hh);
  }
}

// ---------------------------------------------------------------------------
// Kernel 1 (192 blocks):
//  blocks 0..63 : S[b,a] = query@Wq + bq + bm + bl + conv_b@Wl
//  blocks 64..191: a = blk-64: WmT/WlT hi/lo bf16 split-transpose
// ---------------------------------------------------------------------------
__global__ __launch_bounds__(256) void k_qproj(
    const float* __restrict__ query, const float* __restrict__ Wq,
    const float* __restrict__ bq, const float* __restrict__ bm,
    const float* __restrict__ conv_b, const float* __restrict__ Wl,
    const float* __restrict__ bl, const float* __restrict__ Wm,
    float* __restrict__ wsS,
    __bf16* __restrict__ wmtH, __bf16* __restrict__ wmtL,
    __bf16* __restrict__ wltH, __bf16* __restrict__ wltL)
{
  int tid = threadIdx.x;
  if (blockIdx.x < 64) {
    int b = blockIdx.x;
    int a = tid & 127;
    int h = tid >> 7;
    const float* q = query + (size_t)b * DEC;
    int e0 = h * (DEC / 2);
    float sum = 0.f;
    #pragma unroll 8
    for (int e = 0; e < DEC / 2; ++e)
      sum = fmaf(q[e0 + e], Wq[(size_t)(e0 + e) * ADIM + a], sum);
    __shared__ float red[256];
    red[tid] = sum;
    __syncthreads();
    if (h == 0) {
      float s = red[tid] + red[tid + 128];
      float cb = 0.f;
      #pragma unroll
      for (int f = 0; f < NFILT; ++f) cb = fmaf(conv_b[f], Wl[f * ADIM + a], cb);
      wsS[b * ADIM + a] = s + bq[a] + bm[a] + bl[a] + cb;
    }
  } else {
    int a = blockIdx.x - 64;  // 0..127
    for (int e = tid; e < EMB; e += 256) {
      float x = Wm[(size_t)e * ADIM + a];
      __bf16 hh = (__bf16)x;
      wmtH[(size_t)a * EMB + e] = hh;
      wmtL[(size_t)a * EMB + e] = (__bf16)(x - (float)hh);
    }
    if (tid < NFILT) {
      float x = Wl[tid * ADIM + a];
      __bf16 hh = (__bf16)x;
      wltH[a * NFILT + tid] = hh;
      wltL[a * NFILT + tid] = (__bf16)(x - (float)hh);
    }
  }
}

// ---------------------------------------------------------------------------
// Kernel 2: per (tile, b): MFMA energies + online-softmax partials + context
// A = memory tile, split to bf16 h/l in LDS. B = pre-split WmT (L2-resident,
// loaded per-fragment from global). 3-pass split GEMM: ah*bh + al*bh + ah*bl.
// Wave w owns rows [32w,32w+32); frag row r in {0,1}; col group cg in 0..7.
// MFMA 16x16x32 layouts (m89-verified D; standard A/B):
//   A: row=l&15, k=(l>>4)*8+j ; B: col=l&15, k=(l>>4)*8+j ; D: col=l&15, row=(l>>4)*4+j
// ---------------------------------------------------------------------------
__global__ __launch_bounds__(256, 1) void k_energy(
    const float* __restrict__ memory, const float* __restrict__ awc,
    const float* __restrict__ mask,
    const __bf16* __restrict__ wmtH, const __bf16* __restrict__ wmtL,
    const __bf16* __restrict__ wltH, const __bf16* __restrict__ wltL,
    const float* __restrict__ convk,
    const float* __restrict__ V, const float* __restrict__ bV,
    const float* __restrict__ wsS, float* __restrict__ energies,
    float* __restrict__ pm, float* __restrict__ psum, float* __restrict__ pc)
{
  __shared__ __align__(16) __bf16 Ah[TILE_T * APAD];   // 10240 B
  __shared__ __align__(16) __bf16 Al[TILE_T * APAD];   // 10240 B
  __shared__ __align__(16) float scr[1152];            // ckS[992] awcS[158] / eT pT
  __shared__ float r2[8];

  int tid = threadIdx.x;
  int tile = blockIdx.x;
  int b = blockIdx.y;
  int t0 = tile * TILE_T;
  int w = tid >> 6;
  int l = tid & 63;
  int lr = l & 15;   // frag row (A) / col (B,D)
  int lk = l >> 4;   // k-group
  int rowS = tid >> 1;       // staging row 0..127
  int half = tid & 1;        // staging e-half

  float* ckS  = scr;         // [31][32]
  float* awcS = scr + 992;   // [158]
  for (int i = tid; i < KSIZE * NFILT; i += 256) ckS[i] = convk[i];
  for (int i = tid; i < TILE_T + KSIZE - 1; i += 256) {
    int tg = t0 + i - KHALF;
    awcS[i] = (tg >= 0 && tg < T) ? awc[(size_t)b * T + tg] : 0.f;
  }

  // acc init with t-independent S[b, col]
  f32x4 acc[2][8];
  #pragma unroll
  for (int cg = 0; cg < 8; ++cg) {
    float sv = wsS[b * ADIM + cg * 16 + lr];
    f32x4 iv = {sv, sv, sv, sv};
    acc[0][cg] = iv;
    acc[1][cg] = iv;
  }

  const int aoff0 = (32 * w + lr) * APAD + lk * 8;
  const int aoff1 = aoff0 + 16 * APAD;
  const int wbase = rowS * APAD + half * 16;
  const float* abase = memory + ((size_t)b * T + t0 + rowS) * EMB + half * 16;

  float4 ra[4];
  #pragma unroll
  for (int k = 0; k < 4; ++k)
    ra[k] = *reinterpret_cast<const float4*>(abase + k * 4);

  for (int ec = 0; ec < EMB / 32; ++ec) {
    __syncthreads();  // previous chunk's MFMA reads done
    bf16x8 h0, h1, l0, l1;
    cvt8(ra[0], ra[1], h0, l0);
    cvt8(ra[2], ra[3], h1, l1);
    *reinterpret_cast<bf16x8*>(Ah + wbase) = h0;
    *reinterpret_cast<bf16x8*>(Ah + wbase + 8) = h1;
    *reinterpret_cast<bf16x8*>(Al + wbase) = l0;
    *reinterpret_cast<bf16x8*>(Al + wbase + 8) = l1;
    __syncthreads();
    if (ec + 1 < EMB / 32) {  // issue-early next chunk
      #pragma unroll
      for (int k = 0; k < 4; ++k)
        ra[k] = *reinterpret_cast<const float4*>(abase + (ec + 1) * 32 + k * 4);
    }
    bf16x8 ah0 = *reinterpret_cast<const bf16x8*>(Ah + aoff0);
    bf16x8 ah1 = *reinterpret_cast<const bf16x8*>(Ah + aoff1);
    bf16x8 al0 = *reinterpret_cast<const bf16x8*>(Al + aoff0);
    bf16x8 al1 = *reinterpret_cast<const bf16x8*>(Al + aoff1);
    const __bf16* bhp = wmtH + (size_t)lr * EMB + ec * 32 + lk * 8;
    const __bf16* blp = wmtL + (size_t)lr * EMB + ec * 32 + lk * 8;
    #pragma unroll
    for (int cg = 0; cg < 8; ++cg) {
      bf16x8 bh = *reinterpret_cast<const bf16x8*>(bhp + (size_t)cg * 16 * EMB);
      bf16x8 bl = *reinterpret_cast<const bf16x8*>(blp + (size_t)cg * 16 * EMB);
      acc[0][cg] = __builtin_amdgcn_mfma_f32_16x16x32_bf16(ah0, bh, acc[0][cg], 0, 0, 0);
      acc[1][cg] = __builtin_amdgcn_mfma_f32_16x16x32_bf16(ah1, bh, acc[1][cg], 0, 0, 0);
      acc[0][cg] = __builtin_amdgcn_mfma_f32_16x16x32_bf16(al0, bh, acc[0][cg], 0, 0, 0);
      acc[1][cg] = __builtin_amdgcn_mfma_f32_16x16x32_bf16(al1, bh, acc[1][cg], 0, 0, 0);
      acc[0][cg] = __builtin_amdgcn_mfma_f32_16x16x32_bf16(ah0, bl, acc[0][cg], 0, 0, 0);
      acc[1][cg] = __builtin_amdgcn_mfma_f32_16x16x32_bf16(ah1, bl, acc[1][cg], 0, 0, 0);
    }
  }

  // ---- location phase: conv(awc)[t][f] -> A (K=32 chunk), B = WlT h/l ----
  __syncthreads();  // last chunk MFMA reads done
  {
    int t = rowS;
    int f0 = half * 16;
    float lf[16];
    #pragma unroll
    for (int j = 0; j < 16; ++j) lf[j] = 0.f;
    for (int k = 0; k < KSIZE; ++k) {
      float av = awcS[t + k];
      #pragma unroll
      for (int j = 0; j < 16; ++j) lf[j] = fmaf(av, ckS[k * NFILT + f0 + j], lf[j]);
    }
    bf16x8 h0, h1, l0, l1;
    float4 u0 = make_float4(lf[0], lf[1], lf[2], lf[3]);
    float4 u1 = make_float4(lf[4], lf[5], lf[6], lf[7]);
    float4 u2 = make_float4(lf[8], lf[9], lf[10], lf[11]);
    float4 u3 = make_float4(lf[12], lf[13], lf[14], lf[15]);
    cvt8(u0, u1, h0, l0);
    cvt8(u2, u3, h1, l1);
    *reinterpret_cast<bf16x8*>(Ah + wbase) = h0;
    *reinterpret_cast<bf16x8*>(Ah + wbase + 8) = h1;
    *reinterpret_cast<bf16x8*>(Al + wbase) = l0;
    *reinterpret_cast<bf16x8*>(Al + wbase + 8) = l1;
  }
  __syncthreads();
  {
    bf16x8 ah0 = *reinterpret_cast<const bf16x8*>(Ah + aoff0);
    bf16x8 ah1 = *reinterpret_cast<const bf16x8*>(Ah + aoff1);
    bf16x8 al0 = *reinterpret_cast<const bf16x8*>(Al + aoff0);
    bf16x8 al1 = *reinterpret_cast<const bf16x8*>(Al + aoff1);
    const __bf16* bhp = wltH + lr * NFILT + lk * 8;
    const __bf16* blp = wltL + lr * NFILT + lk * 8;
    #pragma unroll
    for (int cg = 0; cg < 8; ++cg) {
      bf16x8 bh = *reinterpret_cast<const bf16x8*>(bhp + cg * 16 * NFILT);
      bf16x8 bl = *reinterpret_cast<const bf16x8*>(blp + cg * 16 * NFILT);
      acc[0][cg] = __builtin_amdgcn_mfma_f32_16x16x32_bf16(ah0, bh, acc[0][cg], 0, 0, 0);
      acc[1][cg] = __builtin_amdgcn_mfma_f32_16x16x32_bf16(ah1, bh, acc[1][cg], 0, 0, 0);
      acc[0][cg] = __builtin_amdgcn_mfma_f32_16x16x32_bf16(al0, bh, acc[0][cg], 0, 0, 0);
      acc[1][cg] = __builtin_amdgcn_mfma_f32_16x16x32_bf16(al1, bh, acc[1][cg], 0, 0, 0);
      acc[0][cg] = __builtin_amdgcn_mfma_f32_16x16x32_bf16(ah0, bl, acc[0][cg], 0, 0, 0);
      acc[1][cg] = __builtin_amdgcn_mfma_f32_16x16x32_bf16(ah1, bl, acc[1][cg], 0, 0, 0);
    }
  }

  // ---- epilogue: E[t] = sum_a tanh(acc) * V[a] + bV + mask*-1e9 ----
  float* eT = scr;        // conv data dead
  float* pT = scr + 128;
  {
    float vv[8];
    #pragma unroll
    for (int cg = 0; cg < 8; ++cg) vv[cg] = V[cg * 16 + lr];
    float bVv = bV[0];
    #pragma unroll
    for (int r = 0; r < 2; ++r) {
      #pragma unroll
      for (int j = 0; j < 4; ++j) {
        float s = 0.f;
        #pragma unroll
        for (int cg = 0; cg < 8; ++cg) s = fmaf(tanhf(acc[r][cg][j]), vv[cg], s);
        s += __shfl_xor(s, 1, 64);
        s += __shfl_xor(s, 2, 64);
        s += __shfl_xor(s, 4, 64);
        s += __shfl_xor(s, 8, 64);
        if (lr == 0) {
          int t = 32 * w + 16 * r + lk * 4 + j;
          float E = s + bVv + mask[(size_t)b * T + t0 + t] * (-1e9f);
          eT[t] = E;
          energies[(size_t)b * T + t0 + t] = E;
        }
      }
    }
  }
  __syncthreads();

  // ---- tile softmax stats + context partial (memory tile is L2-hot) ----
  float E2 = -INFINITY;
  if (tid < 128) E2 = eT[tid];
  float mw = E2;
  #pragma unroll
  for (int d = 1; d < 64; d <<= 1) mw = fmaxf(mw, __shfl_xor(mw, d, 64));
  if (tid < 128 && (tid & 63) == 0) r2[tid >> 6] = mw;
  __syncthreads();
  float mblk = fmaxf(r2[0], r2[1]);
  float pv = 0.f;
  if (tid < 128) { pv = expf(E2 - mblk); pT[tid] = pv; }
  float sw = pv;
  #pragma unroll
  for (int d = 1; d < 64; d <<= 1) sw += __shfl_xor(sw, d, 64);
  if (tid < 128 && (tid & 63) == 0) r2[4 + (tid >> 6)] = sw;
  __syncthreads();
  if (tid == 0) {
    pm[b * NTILE + tile] = mblk;
    psum[b * NTILE + tile] = r2[4] + r2[5];
  }
  {
    int e = tid * 2;
    float c0 = 0.f, c1 = 0.f;
    const float* mrow = memory + ((size_t)b * T + t0) * EMB + e;
    #pragma unroll 4
    for (int t = 0; t < TILE_T; ++t) {
      float p = pT[t];
      float2 mv = *reinterpret_cast<const float2*>(mrow + (size_t)t * EMB);
      c0 = fmaf(p, mv.x, c0);
      c1 = fmaf(p, mv.y, c1);
    }
    float* dst = pc + ((size_t)b * NTILE + tile) * EMB + e;
    dst[0] = c0;
    dst[1] = c1;
  }
}

// ---------------------------------------------------------------------------
// Kernel 3: combine partials -> context, weights
// ---------------------------------------------------------------------------
__global__ __launch_bounds__(256) void k_final(
    const float* __restrict__ energies, const float* __restrict__ pm,
    const float* __restrict__ psum, const float* __restrict__ pc,
    float* __restrict__ out)
{
  int b = blockIdx.x;
  int tid = threadIdx.x;
  __shared__ float scale[NTILE];
  __shared__ float MS[2];
  if (tid < 64) {
    float m = (tid < NTILE) ? pm[b * NTILE + tid] : -INFINITY;
    float M = m;
    #pragma unroll
    for (int d = 1; d < 64; d <<= 1) M = fmaxf(M, __shfl_xor(M, d, 64));
    float sc = (tid < NTILE) ? psum[b * NTILE + tid] * expf(m - M) : 0.f;
    float S = sc;
    #pragma unroll
    for (int d = 1; d < 64; d <<= 1) S += __shfl_xor(S, d, 64);
    if (tid < NTILE) scale[tid] = expf(m - M);
    if (tid == 0) { MS[0] = M; MS[1] = S; }
  }
  __syncthreads();
  float M = MS[0];
  float Sinv = 1.f / MS[1];
  {
    int e = tid * 2;
    float c0 = 0.f, c1 = 0.f;
    const float* src = pc + (size_t)b * NTILE * EMB + e;
    #pragma unroll
    for (int p = 0; p < NTILE; ++p) {
      float s = scale[p];
      float2 v = *reinterpret_cast<const float2*>(src + p * EMB);
      c0 = fmaf(s, v.x, c0);
      c1 = fmaf(s, v.y, c1);
    }
    out[(size_t)b * EMB + e] = c0 * Sinv;
    out[(size_t)b * EMB + e + 1] = c1 * Sinv;
  }
  {
    float* wout = out + B * EMB;
    const float* Eb = energies + (size_t)b * T;
    int t = tid * 8;
    float4 e0 = *reinterpret_cast<const float4*>(Eb + t);
    float4 e1 = *reinterpret_cast<const float4*>(Eb + t + 4);
    float4 w0 = make_float4(expf(e0.x - M) * Sinv, expf(e0.y - M) * Sinv,
                            expf(e0.z - M) * Sinv, expf(e0.w - M) * Sinv);
    float4 w1 = make_float4(expf(e1.x - M) * Sinv, expf(e1.y - M) * Sinv,
                            expf(e1.z - M) * Sinv, expf(e1.w - M) * Sinv);
    *reinterpret_cast<float4*>(wout + (size_t)b * T + t) = w0;
    *reinterpret_cast<float4*>(wout + (size_t)b * T + t + 4) = w1;
  }
}

// ---------------------------------------------------------------------------
extern "C" void kernel_launch(void* const* d_in, const int* in_sizes, int n_in,
                              void* d_out, int out_size, void* d_ws, size_t ws_size,
                              hipStream_t stream)
{
  const float* query  = (const float*)d_in[0];
  const float* memory = (const float*)d_in[1];
  const float* awc    = (const float*)d_in[2];
  const float* mask   = (const float*)d_in[3];
  const float* Wq     = (const float*)d_in[4];
  const float* bq     = (const float*)d_in[5];
  const float* Wm     = (const float*)d_in[6];
  const float* bm     = (const float*)d_in[7];
  const float* convk  = (const float*)d_in[8];
  const float* convb  = (const float*)d_in[9];
  const float* Wl     = (const float*)d_in[10];
  const float* bl     = (const float*)d_in[11];
  const float* V      = (const float*)d_in[12];
  const float* bV     = (const float*)d_in[13];
  float* out = (float*)d_out;
  float* ws  = (float*)d_ws;

  float* wsS      = ws + WS_S;
  float* energies = ws + WS_E;
  float* pm       = ws + WS_PM;
  float* psum     = ws + WS_PS;
  float* pc       = ws + WS_PC;
  __bf16* wmtH = (__bf16*)(ws + WS_WMT_H);
  __bf16* wmtL = (__bf16*)(ws + WS_WMT_L);
  __bf16* wltH = (__bf16*)(ws + WS_WLT_H);
  __bf16* wltL = (__bf16*)(ws + WS_WLT_L);

  k_qproj<<<192, 256, 0, stream>>>(query, Wq, bq, bm, convb, Wl, bl, Wm,
                                   wsS, wmtH, wmtL, wltH, wltL);
  dim3 g2(NTILE, B);
  k_energy<<<g2, 256, 0, stream>>>(memory, awc, mask, wmtH, wmtL, wltH, wltL,
                                   convk, V, bV, wsS, energies, pm, psum, pc);
  k_final<<<B, 256, 0, stream>>>(energies, pm, psum, pc, out);
}